// Round 1
// baseline (642.307 us; speedup 1.0000x reference)
//
#include <hip/hip_runtime.h>
#include <math.h>

#define HID 64
#define NSLOPE 0.2f
#define SB 512

// ---------------- f32 tiled GEMM: C[M,Nc] = A[M,K] @ B[K,Nc], 64x64 tile ----------------
__global__ __launch_bounds__(256) void gemm64(const float* __restrict__ A,
                                              const float* __restrict__ B,
                                              float* __restrict__ C,
                                              int M, int Nc, int K) {
  __shared__ float As[16][68];  // [k][m], padded (68 = 4*17, keeps float4 alignment)
  __shared__ float Bs[16][64];  // [k][n]
  const int tid = threadIdx.x;
  const int ty = tid >> 4, tx = tid & 15;
  const int row0 = blockIdx.x * 64;
  const int col0 = blockIdx.y * 64;
  float acc[4][4] = {};
  for (int k0 = 0; k0 < K; k0 += 16) {
    {  // A tile: 64 rows x 16 k, one float4 per thread
      int r = tid >> 2;
      int kk = (tid & 3) << 2;
      int arow = row0 + r;
      float4 av = make_float4(0.f, 0.f, 0.f, 0.f);
      if (arow < M) av = *reinterpret_cast<const float4*>(&A[(size_t)arow * K + k0 + kk]);
      As[kk + 0][r] = av.x; As[kk + 1][r] = av.y; As[kk + 2][r] = av.z; As[kk + 3][r] = av.w;
    }
    {  // B tile: 16 k x 64 cols
      int c = tid & 63;
      int r0 = tid >> 6;
      #pragma unroll
      for (int j = 0; j < 4; ++j)
        Bs[r0 + 4 * j][c] = B[(size_t)(k0 + r0 + 4 * j) * Nc + col0 + c];
    }
    __syncthreads();
    #pragma unroll
    for (int k = 0; k < 16; ++k) {
      float4 a = *reinterpret_cast<const float4*>(&As[k][ty << 2]);
      float4 b = *reinterpret_cast<const float4*>(&Bs[k][tx << 2]);
      float aa[4] = {a.x, a.y, a.z, a.w};
      float bb[4] = {b.x, b.y, b.z, b.w};
      #pragma unroll
      for (int i = 0; i < 4; ++i)
        #pragma unroll
        for (int j = 0; j < 4; ++j)
          acc[i][j] = fmaf(aa[i], bb[j], acc[i][j]);
    }
    __syncthreads();
  }
  #pragma unroll
  for (int i = 0; i < 4; ++i) {
    int r = row0 + (ty << 2) + i;
    if (r < M) {
      float4 o = make_float4(acc[i][0], acc[i][1], acc[i][2], acc[i][3]);
      *reinterpret_cast<float4*>(&C[(size_t)r * Nc + col0 + (tx << 2)]) = o;
    }
  }
}

// ---------------- per-node attention logits el/er ----------------
__global__ __launch_bounds__(64) void elr_kernel(const float* __restrict__ h,
    const float* __restrict__ al, const float* __restrict__ ar,
    float* __restrict__ el, float* __restrict__ er, int H) {
  int n = blockIdx.x, lane = threadIdx.x;
  const float* hr = h + (size_t)n * H * HID;
  for (int hh = 0; hh < H; ++hh) {
    float v = hr[hh * HID + lane];
    float a = v * al[hh * HID + lane];
    float b = v * ar[hh * HID + lane];
    #pragma unroll
    for (int o = 32; o > 0; o >>= 1) { a += __shfl_xor(a, o); b += __shfl_xor(b, o); }
    if (lane == 0) { el[n * H + hh] = a; er[n * H + hh] = b; }
  }
}

// ---------------- CSR build ----------------
__global__ void k_count(const int* __restrict__ dst, int* __restrict__ deg, int E) {
  int e = blockIdx.x * blockDim.x + threadIdx.x;
  if (e < E) atomicAdd(&deg[dst[e]], 1);
}
__global__ __launch_bounds__(SB) void k_blocksums(const int* __restrict__ deg,
                                                  int* __restrict__ bsums, int n) {
  __shared__ int s[SB];
  int t = threadIdx.x, i = blockIdx.x * SB + t;
  s[t] = (i < n) ? deg[i] : 0;
  __syncthreads();
  for (int o = SB >> 1; o > 0; o >>= 1) { if (t < o) s[t] += s[t + o]; __syncthreads(); }
  if (t == 0) bsums[blockIdx.x] = s[0];
}
__global__ __launch_bounds__(SB) void k_scancarry(const int* __restrict__ bsums,
                                                   int* __restrict__ carry, int nb) {
  __shared__ int s[SB];
  int t = threadIdx.x;
  int v = (t < nb) ? bsums[t] : 0;
  s[t] = v; __syncthreads();
  for (int o = 1; o < SB; o <<= 1) {
    int u = (t >= o) ? s[t - o] : 0;
    __syncthreads(); s[t] += u; __syncthreads();
  }
  if (t < nb) carry[t] = s[t] - v;
}
__global__ __launch_bounds__(SB) void k_offsets(const int* __restrict__ deg,
    const int* __restrict__ carry, int* __restrict__ offs, int n, int E) {
  __shared__ int s[SB];
  int t = threadIdx.x, i = blockIdx.x * SB + t;
  int v = (i < n) ? deg[i] : 0;
  s[t] = v; __syncthreads();
  for (int o = 1; o < SB; o <<= 1) {
    int u = (t >= o) ? s[t - o] : 0;
    __syncthreads(); s[t] += u; __syncthreads();
  }
  if (i < n) offs[i] = carry[blockIdx.x] + s[t] - v;
  if (i == n) offs[n] = E;
}
__global__ void k_fill(const int* __restrict__ src, const int* __restrict__ dst,
                       const int* __restrict__ offs, int* __restrict__ cursor,
                       int* __restrict__ esrc, int E) {
  int e = blockIdx.x * blockDim.x + threadIdx.x;
  if (e < E) {
    int d = dst[e];
    int slot = offs[d] + atomicAdd(&cursor[d], 1);
    esrc[slot] = src[e];
  }
}

// ---------------- per-dst softmax + weighted gather-sum (one wave per dst node) ----------------
template<int H, bool DO_ELU>
__global__ __launch_bounds__(64) void agg_kernel(const float* __restrict__ hbuf,
    const float* __restrict__ el, const float* __restrict__ er,
    const int* __restrict__ offs, const int* __restrict__ esrc,
    const float* __restrict__ bias, float* __restrict__ out) {
  const int n = blockIdx.x, lane = threadIdx.x;
  const int off = offs[n];
  const int deg = offs[n + 1] - off;
  float erh[H], mh[H], sh[H], inv[H], acc[H];
  #pragma unroll
  for (int hh = 0; hh < H; ++hh) {
    erh[hh] = er[n * H + hh]; mh[hh] = -1e30f; sh[hh] = 0.f; acc[hh] = 0.f;
  }
  // pass 1a: segment max per head
  for (int base = 0; base < deg; base += 64) {
    int i = base + lane;
    float eh[H];
    if (i < deg) {
      int s = esrc[off + i];
      #pragma unroll
      for (int hh = 0; hh < H; ++hh) {
        float e = el[s * H + hh] + erh[hh];
        eh[hh] = e > 0.f ? e : NSLOPE * e;
      }
    } else {
      #pragma unroll
      for (int hh = 0; hh < H; ++hh) eh[hh] = -1e30f;
    }
    #pragma unroll
    for (int hh = 0; hh < H; ++hh) {
      float v = eh[hh];
      #pragma unroll
      for (int o = 32; o > 0; o >>= 1) v = fmaxf(v, __shfl_xor(v, o));
      mh[hh] = fmaxf(mh[hh], v);
    }
  }
  // pass 1b: ex = exp(e - m); keep chunks 0..3 (deg<=256) in registers, statically indexed
  auto compute_ex = [&](int i, float (&t)[H]) {
    if (i < deg) {
      int s = esrc[off + i];
      #pragma unroll
      for (int hh = 0; hh < H; ++hh) {
        float e = el[s * H + hh] + erh[hh];
        e = e > 0.f ? e : NSLOPE * e;
        t[hh] = __expf(e - mh[hh]);
      }
    } else {
      #pragma unroll
      for (int hh = 0; hh < H; ++hh) t[hh] = 0.f;
    }
  };
  float ex0[H], ex1[H], ex2[H], ex3[H];
  compute_ex(lane, ex0);
  compute_ex(64 + lane, ex1);
  compute_ex(128 + lane, ex2);
  compute_ex(192 + lane, ex3);
  #pragma unroll
  for (int hh = 0; hh < H; ++hh) sh[hh] = ex0[hh] + ex1[hh] + ex2[hh] + ex3[hh];
  for (int base = 256; base < deg; base += 64) {  // overflow (not expected for this graph)
    float t[H]; compute_ex(base + lane, t);
    #pragma unroll
    for (int hh = 0; hh < H; ++hh) sh[hh] += t[hh];
  }
  #pragma unroll
  for (int hh = 0; hh < H; ++hh) {
    float v = sh[hh];
    #pragma unroll
    for (int o = 32; o > 0; o >>= 1) v += __shfl_xor(v, o);
    inv[hh] = v > 0.f ? 1.f / v : 0.f;
  }
  // pass 2: acc[hh] (dim = lane) += h[src][hh*64+lane] * alpha
  auto pv = [&](int cbase, const float (&exv)[H]) {
    int lim = deg - cbase; lim = lim > 64 ? 64 : lim;
    for (int t = 0; t < lim; ++t) {
      int s = esrc[off + cbase + t];
      const float* hp = hbuf + (size_t)s * (H * HID);
      #pragma unroll
      for (int hh = 0; hh < H; ++hh) {
        float a = __shfl(exv[hh], t) * inv[hh];
        acc[hh] = fmaf(hp[hh * HID + lane], a, acc[hh]);
      }
    }
  };
  if (deg > 0)   pv(0, ex0);
  if (deg > 64)  pv(64, ex1);
  if (deg > 128) pv(128, ex2);
  if (deg > 192) pv(192, ex3);
  for (int i = 256; i < deg; ++i) {  // overflow: recompute alpha (wave-uniform)
    int s = esrc[off + i];
    const float* hp = hbuf + (size_t)s * (H * HID);
    #pragma unroll
    for (int hh = 0; hh < H; ++hh) {
      float e = el[s * H + hh] + erh[hh];
      e = e > 0.f ? e : NSLOPE * e;
      float a = __expf(e - mh[hh]) * inv[hh];
      acc[hh] = fmaf(hp[hh * HID + lane], a, acc[hh]);
    }
  }
  // epilogue: + bias (+ elu)
  #pragma unroll
  for (int hh = 0; hh < H; ++hh) {
    float v = acc[hh] + bias[hh * HID + lane];
    if (DO_ELU) v = v > 0.f ? v : expm1f(v);
    out[(size_t)n * (H * HID) + hh * HID + lane] = v;
  }
}

extern "C" void kernel_launch(void* const* d_in, const int* in_sizes, int n_in,
                              void* d_out, int out_size, void* d_ws, size_t ws_size,
                              hipStream_t stream) {
  const float* feat = (const float*)d_in[0];
  const int* src = (const int*)d_in[1];
  const int* dst = (const int*)d_in[2];
  const float* W1 = (const float*)d_in[3];
  const float* al1 = (const float*)d_in[4];
  const float* ar1 = (const float*)d_in[5];
  const float* b1 = (const float*)d_in[6];
  const float* W2 = (const float*)d_in[7];
  const float* al2 = (const float*)d_in[8];
  const float* ar2 = (const float*)d_in[9];
  const float* b2 = (const float*)d_in[10];
  const float* W3 = (const float*)d_in[11];
  const float* al3 = (const float*)d_in[12];
  const float* ar3 = (const float*)d_in[13];
  const float* b3 = (const float*)d_in[14];
  const int N = in_sizes[0] / 128;  // 50000
  const int E = in_sizes[1];        // 800000

  char* w = (char*)d_ws;
  auto alloc = [&](size_t bytes) {
    void* p = (void*)w;
    w += (bytes + 255) & ~(size_t)255;
    return p;
  };
  float* bufA = (float*)alloc((size_t)N * 256 * 4);  // h (post-GEMM)
  float* bufB = (float*)alloc((size_t)N * 256 * 4);  // layer output / next input
  float* el = (float*)alloc((size_t)N * 4 * 4);
  float* er = (float*)alloc((size_t)N * 4 * 4);
  int* deg = (int*)alloc((size_t)N * 4);
  int* cursor = (int*)alloc((size_t)N * 4);
  int* offs = (int*)alloc((size_t)(N + 1) * 4);
  int nb = (N + SB - 1) / SB;
  int* bsums = (int*)alloc((size_t)nb * 4);
  int* carry = (int*)alloc((size_t)nb * 4);
  int* esrc = (int*)alloc((size_t)E * 4);

  // ---- CSR by dst (graph identical for all 3 layers; built once per call) ----
  hipMemsetAsync(deg, 0, (size_t)N * 4, stream);
  hipMemsetAsync(cursor, 0, (size_t)N * 4, stream);
  int eb = (E + 255) / 256;
  k_count<<<eb, 256, 0, stream>>>(dst, deg, E);
  k_blocksums<<<nb, SB, 0, stream>>>(deg, bsums, N);
  k_scancarry<<<1, SB, 0, stream>>>(bsums, carry, nb);
  k_offsets<<<nb, SB, 0, stream>>>(deg, carry, offs, N, E);
  k_fill<<<eb, 256, 0, stream>>>(src, dst, offs, cursor, esrc, E);

  int mg = (N + 63) / 64;
  // ---- layer 1: feat[N,128] @ W1[128,256] ----
  gemm64<<<dim3(mg, 4), 256, 0, stream>>>(feat, W1, bufA, N, 256, 128);
  elr_kernel<<<N, 64, 0, stream>>>(bufA, al1, ar1, el, er, 4);
  agg_kernel<4, true><<<N, 64, 0, stream>>>(bufA, el, er, offs, esrc, b1, bufB);
  // ---- layer 2: [N,256] @ W2[256,256] ----
  gemm64<<<dim3(mg, 4), 256, 0, stream>>>(bufB, W2, bufA, N, 256, 256);
  elr_kernel<<<N, 64, 0, stream>>>(bufA, al2, ar2, el, er, 4);
  agg_kernel<4, true><<<N, 64, 0, stream>>>(bufA, el, er, offs, esrc, b2, bufB);
  // ---- layer 3: [N,256] @ W3[256,64], single head, mean == identity ----
  gemm64<<<dim3(mg, 1), 256, 0, stream>>>(bufB, W3, bufA, N, 64, 256);
  elr_kernel<<<N, 64, 0, stream>>>(bufA, al3, ar3, el, er, 1);
  agg_kernel<1, false><<<N, 64, 0, stream>>>(bufA, el, er, offs, esrc, b3, (float*)d_out);
}

// Round 2
// 545.241 us; speedup vs baseline: 1.1780x; 1.1780x over previous
//
#include <hip/hip_runtime.h>
#include <math.h>

#define HID 64
#define NSLOPE 0.2f
#define SB 512

typedef __attribute__((ext_vector_type(8))) short short8v;
typedef __attribute__((ext_vector_type(4))) float float4v;

__device__ inline unsigned short f2bf(float x) {
  unsigned u = __float_as_uint(x);
  u += 0x7fffu + ((u >> 16) & 1u);
  return (unsigned short)(u >> 16);
}
__device__ inline float bf2f(unsigned short h) {
  return __uint_as_float(((unsigned)h) << 16);
}

// ---------------- split f32 -> (hi, lo) bf16 planes, elementwise ----------------
__global__ __launch_bounds__(256) void k_split(const float* __restrict__ x,
    unsigned short* __restrict__ hi, unsigned short* __restrict__ lo, int n) {
  int i = blockIdx.x * 256 + threadIdx.x;
  if (i < n) {
    float v = x[i];
    unsigned short h = f2bf(v);
    hi[i] = h;
    lo[i] = f2bf(v - bf2f(h));
  }
}

// ---------------- W [K,N] f32 -> Wt hi/lo [N,K] bf16 ----------------
__global__ __launch_bounds__(256) void k_wsplit(const float* __restrict__ W,
    unsigned short* __restrict__ Whi, unsigned short* __restrict__ Wlo, int K, int N) {
  int i = blockIdx.x * 256 + threadIdx.x;
  if (i < N * K) {
    int n = i / K, k = i - n * K;
    float v = W[(size_t)k * N + n];
    unsigned short h = f2bf(v);
    Whi[i] = h;
    Wlo[i] = f2bf(v - bf2f(h));
  }
}

// ---------------- split-bf16 MFMA GEMM: C[M,Nc] f32 = A @ B, Bt given [N,K] ----
// tile 128x128 (4 waves 2x2, wave=64x64), BK=32, 3 MFMA per frag (hi*hi+hi*lo+lo*hi)
__global__ __launch_bounds__(256) void gemm_split(
    const unsigned short* __restrict__ Ahi, const unsigned short* __restrict__ Alo,
    const unsigned short* __restrict__ Bhi, const unsigned short* __restrict__ Blo,
    float* __restrict__ C, int M, int Nc, int K) {
  __shared__ __align__(16) unsigned short AsHi[128 * 40];
  __shared__ __align__(16) unsigned short AsLo[128 * 40];
  __shared__ __align__(16) unsigned short BsHi[128 * 40];
  __shared__ __align__(16) unsigned short BsLo[128 * 40];
  const int tid = threadIdx.x;
  const int lane = tid & 63, wid = tid >> 6;
  const int wr = wid >> 1, wc = wid & 1;
  const int row0 = blockIdx.y * 128;
  const int col0 = blockIdx.x * 128;
  float4v acc[4][4];
  #pragma unroll
  for (int mi = 0; mi < 4; ++mi)
    #pragma unroll
    for (int ni = 0; ni < 4; ++ni)
      acc[mi][ni] = (float4v){0.f, 0.f, 0.f, 0.f};

  const int sr = tid >> 2;            // 0..63
  const int sc8 = (tid & 3) * 8;      // 0,8,16,24
  const int lr = lane & 15, lk = (lane >> 4) * 8;

  for (int k0 = 0; k0 < K; k0 += 32) {
    // ---- stage 4 tiles ----
    #pragma unroll
    for (int half = 0; half < 2; ++half) {
      int row = sr + half * 64;
      int arow = row0 + row; if (arow > M - 1) arow = M - 1;
      int brow = col0 + row; if (brow > Nc - 1) brow = Nc - 1;
      *(short8v*)&AsHi[row * 40 + sc8] = *(const short8v*)&Ahi[(size_t)arow * K + k0 + sc8];
      *(short8v*)&AsLo[row * 40 + sc8] = *(const short8v*)&Alo[(size_t)arow * K + k0 + sc8];
      *(short8v*)&BsHi[row * 40 + sc8] = *(const short8v*)&Bhi[(size_t)brow * K + k0 + sc8];
      *(short8v*)&BsLo[row * 40 + sc8] = *(const short8v*)&Blo[(size_t)brow * K + k0 + sc8];
    }
    __syncthreads();
    // ---- frag loads ----
    short8v ah[4], alv[4], bh[4], bl[4];
    #pragma unroll
    for (int mi = 0; mi < 4; ++mi) {
      int r = wr * 64 + mi * 16 + lr;
      ah[mi]  = *(const short8v*)&AsHi[r * 40 + lk];
      alv[mi] = *(const short8v*)&AsLo[r * 40 + lk];
    }
    #pragma unroll
    for (int ni = 0; ni < 4; ++ni) {
      int r = wc * 64 + ni * 16 + lr;
      bh[ni] = *(const short8v*)&BsHi[r * 40 + lk];
      bl[ni] = *(const short8v*)&BsLo[r * 40 + lk];
    }
    // ---- 48 MFMA ----
    #pragma unroll
    for (int mi = 0; mi < 4; ++mi)
      #pragma unroll
      for (int ni = 0; ni < 4; ++ni) {
        acc[mi][ni] = __builtin_amdgcn_mfma_f32_16x16x32_bf16(ah[mi], bh[ni], acc[mi][ni], 0, 0, 0);
        acc[mi][ni] = __builtin_amdgcn_mfma_f32_16x16x32_bf16(ah[mi], bl[ni], acc[mi][ni], 0, 0, 0);
        acc[mi][ni] = __builtin_amdgcn_mfma_f32_16x16x32_bf16(alv[mi], bh[ni], acc[mi][ni], 0, 0, 0);
      }
    __syncthreads();
  }
  // ---- store C f32 ----
  #pragma unroll
  for (int mi = 0; mi < 4; ++mi) {
    int rbase = row0 + wr * 64 + mi * 16 + (lane >> 4) * 4;
    #pragma unroll
    for (int ni = 0; ni < 4; ++ni) {
      int cc = col0 + wc * 64 + ni * 16 + (lane & 15);
      if (cc < Nc) {
        #pragma unroll
        for (int q = 0; q < 4; ++q) {
          int rr = rbase + q;
          if (rr < M) C[(size_t)rr * Nc + cc] = acc[mi][ni][q];
        }
      }
    }
  }
}

// ---------------- per-node attention logits el/er ----------------
__global__ __launch_bounds__(64) void elr_kernel(const float* __restrict__ h,
    const float* __restrict__ al, const float* __restrict__ ar,
    float* __restrict__ el, float* __restrict__ er, int H) {
  int n = blockIdx.x, lane = threadIdx.x;
  const float* hr = h + (size_t)n * H * HID;
  for (int hh = 0; hh < H; ++hh) {
    float v = hr[hh * HID + lane];
    float a = v * al[hh * HID + lane];
    float b = v * ar[hh * HID + lane];
    #pragma unroll
    for (int o = 32; o > 0; o >>= 1) { a += __shfl_xor(a, o); b += __shfl_xor(b, o); }
    if (lane == 0) { el[n * H + hh] = a; er[n * H + hh] = b; }
  }
}

// ---------------- CSR build ----------------
__global__ void k_count(const int* __restrict__ dst, int* __restrict__ deg, int E) {
  int e = blockIdx.x * blockDim.x + threadIdx.x;
  if (e < E) atomicAdd(&deg[dst[e]], 1);
}
__global__ __launch_bounds__(SB) void k_blocksums(const int* __restrict__ deg,
                                                  int* __restrict__ bsums, int n) {
  __shared__ int s[SB];
  int t = threadIdx.x, i = blockIdx.x * SB + t;
  s[t] = (i < n) ? deg[i] : 0;
  __syncthreads();
  for (int o = SB >> 1; o > 0; o >>= 1) { if (t < o) s[t] += s[t + o]; __syncthreads(); }
  if (t == 0) bsums[blockIdx.x] = s[0];
}
__global__ __launch_bounds__(SB) void k_scancarry(const int* __restrict__ bsums,
                                                   int* __restrict__ carry, int nb) {
  __shared__ int s[SB];
  int t = threadIdx.x;
  int v = (t < nb) ? bsums[t] : 0;
  s[t] = v; __syncthreads();
  for (int o = 1; o < SB; o <<= 1) {
    int u = (t >= o) ? s[t - o] : 0;
    __syncthreads(); s[t] += u; __syncthreads();
  }
  if (t < nb) carry[t] = s[t] - v;
}
__global__ __launch_bounds__(SB) void k_offsets(const int* __restrict__ deg,
    const int* __restrict__ carry, int* __restrict__ offs, int n, int E) {
  __shared__ int s[SB];
  int t = threadIdx.x, i = blockIdx.x * SB + t;
  int v = (i < n) ? deg[i] : 0;
  s[t] = v; __syncthreads();
  for (int o = 1; o < SB; o <<= 1) {
    int u = (t >= o) ? s[t - o] : 0;
    __syncthreads(); s[t] += u; __syncthreads();
  }
  if (i < n) offs[i] = carry[blockIdx.x] + s[t] - v;
  if (i == n) offs[n] = E;
}
__global__ void k_fill(const int* __restrict__ src, const int* __restrict__ dst,
                       const int* __restrict__ offs, int* __restrict__ cursor,
                       int* __restrict__ esrc, int E) {
  int e = blockIdx.x * blockDim.x + threadIdx.x;
  if (e < E) {
    int d = dst[e];
    int slot = offs[d] + atomicAdd(&cursor[d], 1);
    esrc[slot] = src[e];
  }
}

// ---------------- per-dst softmax + weighted gather-sum (one wave per dst node) ----------------
// SPLITOUT: write hi/lo bf16 planes (next layer's GEMM A); else write f32 out.
template<int H, bool DO_ELU, bool SPLITOUT>
__global__ __launch_bounds__(64) void agg_kernel(const float* __restrict__ hbuf,
    const float* __restrict__ el, const float* __restrict__ er,
    const int* __restrict__ offs, const int* __restrict__ esrc,
    const float* __restrict__ bias,
    unsigned short* __restrict__ outHi, unsigned short* __restrict__ outLo,
    float* __restrict__ outF) {
  const int n = blockIdx.x, lane = threadIdx.x;
  const int off = offs[n];
  const int deg = offs[n + 1] - off;
  float erh[H], mh[H], sh[H], inv[H], acc[H];
  #pragma unroll
  for (int hh = 0; hh < H; ++hh) {
    erh[hh] = er[n * H + hh]; mh[hh] = -1e30f; sh[hh] = 0.f; acc[hh] = 0.f;
  }
  // pass 1a: segment max per head
  for (int base = 0; base < deg; base += 64) {
    int i = base + lane;
    float eh[H];
    if (i < deg) {
      int s = esrc[off + i];
      #pragma unroll
      for (int hh = 0; hh < H; ++hh) {
        float e = el[s * H + hh] + erh[hh];
        eh[hh] = e > 0.f ? e : NSLOPE * e;
      }
    } else {
      #pragma unroll
      for (int hh = 0; hh < H; ++hh) eh[hh] = -1e30f;
    }
    #pragma unroll
    for (int hh = 0; hh < H; ++hh) {
      float v = eh[hh];
      #pragma unroll
      for (int o = 32; o > 0; o >>= 1) v = fmaxf(v, __shfl_xor(v, o));
      mh[hh] = fmaxf(mh[hh], v);
    }
  }
  // pass 1b: ex = exp(e - m); chunks 0..3 (deg<=256) in registers, statically indexed
  auto compute_ex = [&](int i, float (&t)[H]) {
    if (i < deg) {
      int s = esrc[off + i];
      #pragma unroll
      for (int hh = 0; hh < H; ++hh) {
        float e = el[s * H + hh] + erh[hh];
        e = e > 0.f ? e : NSLOPE * e;
        t[hh] = __expf(e - mh[hh]);
      }
    } else {
      #pragma unroll
      for (int hh = 0; hh < H; ++hh) t[hh] = 0.f;
    }
  };
  float ex0[H], ex1[H], ex2[H], ex3[H];
  compute_ex(lane, ex0);
  compute_ex(64 + lane, ex1);
  compute_ex(128 + lane, ex2);
  compute_ex(192 + lane, ex3);
  #pragma unroll
  for (int hh = 0; hh < H; ++hh) sh[hh] = ex0[hh] + ex1[hh] + ex2[hh] + ex3[hh];
  for (int base = 256; base < deg; base += 64) {
    float t[H]; compute_ex(base + lane, t);
    #pragma unroll
    for (int hh = 0; hh < H; ++hh) sh[hh] += t[hh];
  }
  #pragma unroll
  for (int hh = 0; hh < H; ++hh) {
    float v = sh[hh];
    #pragma unroll
    for (int o = 32; o > 0; o >>= 1) v += __shfl_xor(v, o);
    inv[hh] = v > 0.f ? 1.f / v : 0.f;
  }
  // pass 2: acc[hh] (dim = lane) += h[src][hh*64+lane] * alpha, unrolled x4 for MLP
  auto pv = [&](int cbase, const float (&exv)[H]) {
    int lim = deg - cbase; lim = lim > 64 ? 64 : lim;
    int t = 0;
    for (; t + 4 <= lim; t += 4) {
      int s0 = esrc[off + cbase + t + 0];
      int s1 = esrc[off + cbase + t + 1];
      int s2 = esrc[off + cbase + t + 2];
      int s3 = esrc[off + cbase + t + 3];
      const float* p0 = hbuf + (size_t)s0 * (H * HID);
      const float* p1 = hbuf + (size_t)s1 * (H * HID);
      const float* p2 = hbuf + (size_t)s2 * (H * HID);
      const float* p3 = hbuf + (size_t)s3 * (H * HID);
      #pragma unroll
      for (int hh = 0; hh < H; ++hh) {
        float a0 = __shfl(exv[hh], t + 0) * inv[hh];
        float a1 = __shfl(exv[hh], t + 1) * inv[hh];
        float a2 = __shfl(exv[hh], t + 2) * inv[hh];
        float a3 = __shfl(exv[hh], t + 3) * inv[hh];
        float v0 = p0[hh * HID + lane], v1 = p1[hh * HID + lane];
        float v2 = p2[hh * HID + lane], v3 = p3[hh * HID + lane];
        acc[hh] = fmaf(v0, a0, acc[hh]);
        acc[hh] = fmaf(v1, a1, acc[hh]);
        acc[hh] = fmaf(v2, a2, acc[hh]);
        acc[hh] = fmaf(v3, a3, acc[hh]);
      }
    }
    for (; t < lim; ++t) {
      int s = esrc[off + cbase + t];
      const float* hp = hbuf + (size_t)s * (H * HID);
      #pragma unroll
      for (int hh = 0; hh < H; ++hh) {
        float a = __shfl(exv[hh], t) * inv[hh];
        acc[hh] = fmaf(hp[hh * HID + lane], a, acc[hh]);
      }
    }
  };
  if (deg > 0)   pv(0, ex0);
  if (deg > 64)  pv(64, ex1);
  if (deg > 128) pv(128, ex2);
  if (deg > 192) pv(192, ex3);
  for (int i = 256; i < deg; ++i) {  // overflow: recompute alpha (wave-uniform)
    int s = esrc[off + i];
    const float* hp = hbuf + (size_t)s * (H * HID);
    #pragma unroll
    for (int hh = 0; hh < H; ++hh) {
      float e = el[s * H + hh] + erh[hh];
      e = e > 0.f ? e : NSLOPE * e;
      float a = __expf(e - mh[hh]) * inv[hh];
      acc[hh] = fmaf(hp[hh * HID + lane], a, acc[hh]);
    }
  }
  // epilogue
  #pragma unroll
  for (int hh = 0; hh < H; ++hh) {
    float v = acc[hh] + bias[hh * HID + lane];
    if (DO_ELU) v = v > 0.f ? v : expm1f(v);
    size_t oi = (size_t)n * (H * HID) + hh * HID + lane;
    if (SPLITOUT) {
      unsigned short hb = f2bf(v);
      outHi[oi] = hb;
      outLo[oi] = f2bf(v - bf2f(hb));
    } else {
      outF[oi] = v;
    }
  }
}

extern "C" void kernel_launch(void* const* d_in, const int* in_sizes, int n_in,
                              void* d_out, int out_size, void* d_ws, size_t ws_size,
                              hipStream_t stream) {
  const float* feat = (const float*)d_in[0];
  const int* src = (const int*)d_in[1];
  const int* dst = (const int*)d_in[2];
  const float* W1 = (const float*)d_in[3];
  const float* al1 = (const float*)d_in[4];
  const float* ar1 = (const float*)d_in[5];
  const float* b1 = (const float*)d_in[6];
  const float* W2 = (const float*)d_in[7];
  const float* al2 = (const float*)d_in[8];
  const float* ar2 = (const float*)d_in[9];
  const float* b2 = (const float*)d_in[10];
  const float* W3 = (const float*)d_in[11];
  const float* al3 = (const float*)d_in[12];
  const float* ar3 = (const float*)d_in[13];
  const float* b3 = (const float*)d_in[14];
  const int N = in_sizes[0] / 128;  // 50000
  const int E = in_sizes[1];        // 800000

  char* w = (char*)d_ws;
  auto alloc = [&](size_t bytes) {
    void* p = (void*)w;
    w += (bytes + 255) & ~(size_t)255;
    return p;
  };
  unsigned short* pHi = (unsigned short*)alloc((size_t)N * 256 * 2);  // GEMM A hi
  unsigned short* pLo = (unsigned short*)alloc((size_t)N * 256 * 2);  // GEMM A lo
  float* Cbuf = (float*)alloc((size_t)N * 256 * 4);                   // post-GEMM h (f32)
  float* el = (float*)alloc((size_t)N * 4 * 4);
  float* er = (float*)alloc((size_t)N * 4 * 4);
  int* deg = (int*)alloc((size_t)N * 4);
  int* cursor = (int*)alloc((size_t)N * 4);
  int* offs = (int*)alloc((size_t)(N + 1) * 4);
  int nb = (N + SB - 1) / SB;
  int* bsums = (int*)alloc((size_t)nb * 4);
  int* carry = (int*)alloc((size_t)nb * 4);
  int* esrc = (int*)alloc((size_t)E * 4);
  unsigned short* W1h = (unsigned short*)alloc((size_t)256 * 128 * 2);
  unsigned short* W1l = (unsigned short*)alloc((size_t)256 * 128 * 2);
  unsigned short* W2h = (unsigned short*)alloc((size_t)256 * 256 * 2);
  unsigned short* W2l = (unsigned short*)alloc((size_t)256 * 256 * 2);
  unsigned short* W3h = (unsigned short*)alloc((size_t)64 * 256 * 2);
  unsigned short* W3l = (unsigned short*)alloc((size_t)64 * 256 * 2);

  // ---- CSR by dst ----
  hipMemsetAsync(deg, 0, (size_t)N * 4, stream);
  hipMemsetAsync(cursor, 0, (size_t)N * 4, stream);
  int eb = (E + 255) / 256;
  k_count<<<eb, 256, 0, stream>>>(dst, deg, E);
  k_blocksums<<<nb, SB, 0, stream>>>(deg, bsums, N);
  k_scancarry<<<1, SB, 0, stream>>>(bsums, carry, nb);
  k_offsets<<<nb, SB, 0, stream>>>(deg, carry, offs, N, E);
  k_fill<<<eb, 256, 0, stream>>>(src, dst, offs, cursor, esrc, E);

  // ---- weight transpose+split ----
  k_wsplit<<<(256 * 128 + 255) / 256, 256, 0, stream>>>(W1, W1h, W1l, 128, 256);
  k_wsplit<<<(256 * 256 + 255) / 256, 256, 0, stream>>>(W2, W2h, W2l, 256, 256);
  k_wsplit<<<(64 * 256 + 255) / 256, 256, 0, stream>>>(W3, W3h, W3l, 256, 64);

  // ---- feat split ----
  k_split<<<((N * 128) + 255) / 256, 256, 0, stream>>>(feat, pHi, pLo, N * 128);

  int rg = (N + 127) / 128;  // 391
  // ---- layer 1: [N,128] @ W1 -> [N,256] ----
  gemm_split<<<dim3(2, rg), 256, 0, stream>>>(pHi, pLo, W1h, W1l, Cbuf, N, 256, 128);
  elr_kernel<<<N, 64, 0, stream>>>(Cbuf, al1, ar1, el, er, 4);
  agg_kernel<4, true, true><<<N, 64, 0, stream>>>(Cbuf, el, er, offs, esrc, b1, pHi, pLo, nullptr);
  // ---- layer 2: [N,256] @ W2 -> [N,256] ----
  gemm_split<<<dim3(2, rg), 256, 0, stream>>>(pHi, pLo, W2h, W2l, Cbuf, N, 256, 256);
  elr_kernel<<<N, 64, 0, stream>>>(Cbuf, al2, ar2, el, er, 4);
  agg_kernel<4, true, true><<<N, 64, 0, stream>>>(Cbuf, el, er, offs, esrc, b2, pHi, pLo, nullptr);
  // ---- layer 3: [N,256] @ W3 -> [N,64], single head, mean == identity ----
  gemm_split<<<dim3(1, rg), 256, 0, stream>>>(pHi, pLo, W3h, W3l, Cbuf, N, 64, 256);
  elr_kernel<<<N, 64, 0, stream>>>(Cbuf, al3, ar3, el, er, 1);
  agg_kernel<1, false, false><<<N, 64, 0, stream>>>(Cbuf, el, er, offs, esrc, b3, nullptr, nullptr, (float*)d_out);
}

// Round 3
// 508.212 us; speedup vs baseline: 1.2639x; 1.0729x over previous
//
#include <hip/hip_runtime.h>
#include <math.h>

#define HID 64
#define NSLOPE 0.2f
#define SB 512

typedef __attribute__((ext_vector_type(8))) short short8v;
typedef __attribute__((ext_vector_type(4))) float float4v;

__device__ inline unsigned short f2bf(float x) {
  unsigned u = __float_as_uint(x);
  u += 0x7fffu + ((u >> 16) & 1u);
  return (unsigned short)(u >> 16);
}
__device__ inline float bf2f(unsigned short h) {
  return __uint_as_float(((unsigned)h) << 16);
}
__device__ inline float bflo(unsigned u) { return __uint_as_float(u << 16); }
__device__ inline float bfhi(unsigned u) { return __uint_as_float(u & 0xffff0000u); }

// ---------------- split f32 -> (hi, lo) bf16 planes, elementwise ----------------
__global__ __launch_bounds__(256) void k_split(const float* __restrict__ x,
    unsigned short* __restrict__ hi, unsigned short* __restrict__ lo, int n) {
  int i = blockIdx.x * 256 + threadIdx.x;
  if (i < n) {
    float v = x[i];
    unsigned short h = f2bf(v);
    hi[i] = h;
    lo[i] = f2bf(v - bf2f(h));
  }
}

// ---------------- W [K,N] f32 -> Wt hi/lo [N,K] bf16 ----------------
__global__ __launch_bounds__(256) void k_wsplit(const float* __restrict__ W,
    unsigned short* __restrict__ Whi, unsigned short* __restrict__ Wlo, int K, int N) {
  int i = blockIdx.x * 256 + threadIdx.x;
  if (i < N * K) {
    int n = i / K, k = i - n * K;
    float v = W[(size_t)k * N + n];
    unsigned short h = f2bf(v);
    Whi[i] = h;
    Wlo[i] = f2bf(v - bf2f(h));
  }
}

// ---------------- split-bf16 MFMA GEMM + packed-bf16 gather copy ----------------
// C[M,Nc] f32 = (Ahi+Alo) @ (Bhi+Blo)^T, Bt given [N,K]. Also writes
// Gp[m*Nc + (c&63)*H + (c>>6)] = bf16(C[m,c])  (head-minor packed gather layout).
__global__ __launch_bounds__(256) void gemm_split(
    const unsigned short* __restrict__ Ahi, const unsigned short* __restrict__ Alo,
    const unsigned short* __restrict__ Bhi, const unsigned short* __restrict__ Blo,
    float* __restrict__ C, unsigned short* __restrict__ Gp, int M, int Nc, int K, int H) {
  __shared__ __align__(16) unsigned short AsHi[128 * 40];
  __shared__ __align__(16) unsigned short AsLo[128 * 40];
  __shared__ __align__(16) unsigned short BsHi[128 * 40];
  __shared__ __align__(16) unsigned short BsLo[128 * 40];
  const int tid = threadIdx.x;
  const int lane = tid & 63, wid = tid >> 6;
  const int wr = wid >> 1, wc = wid & 1;
  const int row0 = blockIdx.y * 128;
  const int col0 = blockIdx.x * 128;
  float4v acc[4][4];
  #pragma unroll
  for (int mi = 0; mi < 4; ++mi)
    #pragma unroll
    for (int ni = 0; ni < 4; ++ni)
      acc[mi][ni] = (float4v){0.f, 0.f, 0.f, 0.f};

  const int sr = tid >> 2;            // 0..63
  const int sc8 = (tid & 3) * 8;      // 0,8,16,24
  const int lr = lane & 15, lk = (lane >> 4) * 8;

  for (int k0 = 0; k0 < K; k0 += 32) {
    #pragma unroll
    for (int half = 0; half < 2; ++half) {
      int row = sr + half * 64;
      int arow = row0 + row; if (arow > M - 1) arow = M - 1;
      int brow = col0 + row; if (brow > Nc - 1) brow = Nc - 1;
      *(short8v*)&AsHi[row * 40 + sc8] = *(const short8v*)&Ahi[(size_t)arow * K + k0 + sc8];
      *(short8v*)&AsLo[row * 40 + sc8] = *(const short8v*)&Alo[(size_t)arow * K + k0 + sc8];
      *(short8v*)&BsHi[row * 40 + sc8] = *(const short8v*)&Bhi[(size_t)brow * K + k0 + sc8];
      *(short8v*)&BsLo[row * 40 + sc8] = *(const short8v*)&Blo[(size_t)brow * K + k0 + sc8];
    }
    __syncthreads();
    short8v ah[4], alv[4], bh[4], bl[4];
    #pragma unroll
    for (int mi = 0; mi < 4; ++mi) {
      int r = wr * 64 + mi * 16 + lr;
      ah[mi]  = *(const short8v*)&AsHi[r * 40 + lk];
      alv[mi] = *(const short8v*)&AsLo[r * 40 + lk];
    }
    #pragma unroll
    for (int ni = 0; ni < 4; ++ni) {
      int r = wc * 64 + ni * 16 + lr;
      bh[ni] = *(const short8v*)&BsHi[r * 40 + lk];
      bl[ni] = *(const short8v*)&BsLo[r * 40 + lk];
    }
    #pragma unroll
    for (int mi = 0; mi < 4; ++mi)
      #pragma unroll
      for (int ni = 0; ni < 4; ++ni) {
        acc[mi][ni] = __builtin_amdgcn_mfma_f32_16x16x32_bf16(ah[mi], bh[ni], acc[mi][ni], 0, 0, 0);
        acc[mi][ni] = __builtin_amdgcn_mfma_f32_16x16x32_bf16(ah[mi], bl[ni], acc[mi][ni], 0, 0, 0);
        acc[mi][ni] = __builtin_amdgcn_mfma_f32_16x16x32_bf16(alv[mi], bh[ni], acc[mi][ni], 0, 0, 0);
      }
    __syncthreads();
  }
  #pragma unroll
  for (int mi = 0; mi < 4; ++mi) {
    int rbase = row0 + wr * 64 + mi * 16 + (lane >> 4) * 4;
    #pragma unroll
    for (int ni = 0; ni < 4; ++ni) {
      int cc = col0 + wc * 64 + ni * 16 + (lane & 15);
      if (cc < Nc) {
        int gcol = (cc & 63) * H + (cc >> 6);
        #pragma unroll
        for (int q = 0; q < 4; ++q) {
          int rr = rbase + q;
          if (rr < M) {
            float v = acc[mi][ni][q];
            C[(size_t)rr * Nc + cc] = v;
            Gp[(size_t)rr * Nc + gcol] = f2bf(v);
          }
        }
      }
    }
  }
}

// ---------------- per-node attention logits el/er ----------------
__global__ __launch_bounds__(64) void elr_kernel(const float* __restrict__ h,
    const float* __restrict__ al, const float* __restrict__ ar,
    float* __restrict__ el, float* __restrict__ er, int H) {
  int n = blockIdx.x, lane = threadIdx.x;
  const float* hr = h + (size_t)n * H * HID;
  for (int hh = 0; hh < H; ++hh) {
    float v = hr[hh * HID + lane];
    float a = v * al[hh * HID + lane];
    float b = v * ar[hh * HID + lane];
    #pragma unroll
    for (int o = 32; o > 0; o >>= 1) { a += __shfl_xor(a, o); b += __shfl_xor(b, o); }
    if (lane == 0) { el[n * H + hh] = a; er[n * H + hh] = b; }
  }
}

// ---------------- CSR build ----------------
__global__ void k_count(const int* __restrict__ dst, int* __restrict__ deg, int E) {
  int e = blockIdx.x * blockDim.x + threadIdx.x;
  if (e < E) atomicAdd(&deg[dst[e]], 1);
}
__global__ __launch_bounds__(SB) void k_blocksums(const int* __restrict__ deg,
                                                  int* __restrict__ bsums, int n) {
  __shared__ int s[SB];
  int t = threadIdx.x, i = blockIdx.x * SB + t;
  s[t] = (i < n) ? deg[i] : 0;
  __syncthreads();
  for (int o = SB >> 1; o > 0; o >>= 1) { if (t < o) s[t] += s[t + o]; __syncthreads(); }
  if (t == 0) bsums[blockIdx.x] = s[0];
}
__global__ __launch_bounds__(SB) void k_scancarry(const int* __restrict__ bsums,
                                                   int* __restrict__ carry, int nb) {
  __shared__ int s[SB];
  int t = threadIdx.x;
  int v = (t < nb) ? bsums[t] : 0;
  s[t] = v; __syncthreads();
  for (int o = 1; o < SB; o <<= 1) {
    int u = (t >= o) ? s[t - o] : 0;
    __syncthreads(); s[t] += u; __syncthreads();
  }
  if (t < nb) carry[t] = s[t] - v;
}
__global__ __launch_bounds__(SB) void k_offsets(const int* __restrict__ deg,
    const int* __restrict__ carry, int* __restrict__ offs, int n, int E) {
  __shared__ int s[SB];
  int t = threadIdx.x, i = blockIdx.x * SB + t;
  int v = (i < n) ? deg[i] : 0;
  s[t] = v; __syncthreads();
  for (int o = 1; o < SB; o <<= 1) {
    int u = (t >= o) ? s[t - o] : 0;
    __syncthreads(); s[t] += u; __syncthreads();
  }
  if (i < n) offs[i] = carry[blockIdx.x] + s[t] - v;
  if (i == n) offs[n] = E;
}
__global__ void k_fill(const int* __restrict__ src, const int* __restrict__ dst,
                       const int* __restrict__ offs, int* __restrict__ cursor,
                       int* __restrict__ esrc, int E) {
  int e = blockIdx.x * blockDim.x + threadIdx.x;
  if (e < E) {
    int d = dst[e];
    int slot = offs[d] + atomicAdd(&cursor[d], 1);
    esrc[slot] = src[e];
  }
}

// ---------------- per-dst softmax + weighted gather-sum (one wave per dst node) ----
// Gather reads packed bf16 Gp ([n][d][h]); coefficients from f32 el/er (exact path).
// SPLITOUT: write hi/lo bf16 planes (next layer's GEMM A); else write f32 out.
template<int H, bool DO_ELU, bool SPLITOUT>
__global__ __launch_bounds__(64) void agg_kernel(const unsigned short* __restrict__ gp,
    const float* __restrict__ el, const float* __restrict__ er,
    const int* __restrict__ offs, const int* __restrict__ esrc,
    const float* __restrict__ bias,
    unsigned short* __restrict__ outHi, unsigned short* __restrict__ outLo,
    float* __restrict__ outF) {
  const int n = blockIdx.x, lane = threadIdx.x;
  const int off = offs[n];
  const int deg = offs[n + 1] - off;
  float erh[H], mh[H], sh[H], inv[H], acc[H];
  #pragma unroll
  for (int hh = 0; hh < H; ++hh) {
    erh[hh] = er[n * H + hh]; mh[hh] = -1e30f; sh[hh] = 0.f; acc[hh] = 0.f;
  }
  // pass 1a: segment max per head
  for (int base = 0; base < deg; base += 64) {
    int i = base + lane;
    float eh[H];
    if (i < deg) {
      int s = esrc[off + i];
      #pragma unroll
      for (int hh = 0; hh < H; ++hh) {
        float e = el[s * H + hh] + erh[hh];
        eh[hh] = e > 0.f ? e : NSLOPE * e;
      }
    } else {
      #pragma unroll
      for (int hh = 0; hh < H; ++hh) eh[hh] = -1e30f;
    }
    #pragma unroll
    for (int hh = 0; hh < H; ++hh) {
      float v = eh[hh];
      #pragma unroll
      for (int o = 32; o > 0; o >>= 1) v = fmaxf(v, __shfl_xor(v, o));
      mh[hh] = fmaxf(mh[hh], v);
    }
  }
  // pass 1b: ex = exp(e - m); chunks 0..3 (deg<=256) in registers, statically indexed
  auto compute_ex = [&](int i, float (&t)[H]) {
    if (i < deg) {
      int s = esrc[off + i];
      #pragma unroll
      for (int hh = 0; hh < H; ++hh) {
        float e = el[s * H + hh] + erh[hh];
        e = e > 0.f ? e : NSLOPE * e;
        t[hh] = __expf(e - mh[hh]);
      }
    } else {
      #pragma unroll
      for (int hh = 0; hh < H; ++hh) t[hh] = 0.f;
    }
  };
  float ex0[H], ex1[H], ex2[H], ex3[H];
  compute_ex(lane, ex0);
  compute_ex(64 + lane, ex1);
  compute_ex(128 + lane, ex2);
  compute_ex(192 + lane, ex3);
  #pragma unroll
  for (int hh = 0; hh < H; ++hh) sh[hh] = ex0[hh] + ex1[hh] + ex2[hh] + ex3[hh];
  for (int base = 256; base < deg; base += 64) {
    float t[H]; compute_ex(base + lane, t);
    #pragma unroll
    for (int hh = 0; hh < H; ++hh) sh[hh] += t[hh];
  }
  #pragma unroll
  for (int hh = 0; hh < H; ++hh) {
    float v = sh[hh];
    #pragma unroll
    for (int o = 32; o > 0; o >>= 1) v += __shfl_xor(v, o);
    inv[hh] = v > 0.f ? 1.f / v : 0.f;
  }
  // pre-scale ex by 1/s so pass 2's alpha is a bare shfl
  #pragma unroll
  for (int hh = 0; hh < H; ++hh) {
    ex0[hh] *= inv[hh]; ex1[hh] *= inv[hh]; ex2[hh] *= inv[hh]; ex3[hh] *= inv[hh];
  }
  // pass 2: gather packed bf16 rows, weighted accumulate (8-wide unroll)
  auto pv = [&](int cbase, const float (&exv)[H]) {
    int lim = deg - cbase; lim = lim > 64 ? 64 : lim;
    int t = 0;
    for (; t + 8 <= lim; t += 8) {
      int s[8];
      #pragma unroll
      for (int j = 0; j < 8; ++j) s[j] = esrc[off + cbase + t + j];
      if (H == 4) {
        uint2 g[8];
        #pragma unroll
        for (int j = 0; j < 8; ++j)
          g[j] = *(const uint2*)&gp[(size_t)s[j] * 256 + lane * 4];
        #pragma unroll
        for (int j = 0; j < 8; ++j) {
          acc[0] = fmaf(bflo(g[j].x), __shfl(exv[0], t + j), acc[0]);
          acc[1] = fmaf(bfhi(g[j].x), __shfl(exv[1], t + j), acc[1]);
          acc[2] = fmaf(bflo(g[j].y), __shfl(exv[2], t + j), acc[2]);
          acc[3] = fmaf(bfhi(g[j].y), __shfl(exv[3], t + j), acc[3]);
        }
      } else {
        unsigned short g[8];
        #pragma unroll
        for (int j = 0; j < 8; ++j) g[j] = gp[(size_t)s[j] * 64 + lane];
        #pragma unroll
        for (int j = 0; j < 8; ++j)
          acc[0] = fmaf(bf2f(g[j]), __shfl(exv[0], t + j), acc[0]);
      }
    }
    for (; t < lim; ++t) {
      int s = esrc[off + cbase + t];
      if (H == 4) {
        uint2 g = *(const uint2*)&gp[(size_t)s * 256 + lane * 4];
        acc[0] = fmaf(bflo(g.x), __shfl(exv[0], t), acc[0]);
        acc[1] = fmaf(bfhi(g.x), __shfl(exv[1], t), acc[1]);
        acc[2] = fmaf(bflo(g.y), __shfl(exv[2], t), acc[2]);
        acc[3] = fmaf(bfhi(g.y), __shfl(exv[3], t), acc[3]);
      } else {
        acc[0] = fmaf(bf2f(gp[(size_t)s * 64 + lane]), __shfl(exv[0], t), acc[0]);
      }
    }
  };
  if (deg > 0)   pv(0, ex0);
  if (deg > 64)  pv(64, ex1);
  if (deg > 128) pv(128, ex2);
  if (deg > 192) pv(192, ex3);
  for (int i = 256; i < deg; ++i) {  // overflow: recompute alpha (wave-uniform)
    int s = esrc[off + i];
    #pragma unroll
    for (int hh = 0; hh < H; ++hh) {
      float e = el[s * H + hh] + erh[hh];
      e = e > 0.f ? e : NSLOPE * e;
      float a = __expf(e - mh[hh]) * inv[hh];
      float v = (H == 4) ? bf2f(gp[(size_t)s * 256 + lane * 4 + hh])
                         : bf2f(gp[(size_t)s * 64 + lane]);
      acc[hh] = fmaf(v, a, acc[hh]);
    }
  }
  // epilogue
  #pragma unroll
  for (int hh = 0; hh < H; ++hh) {
    float v = acc[hh] + bias[hh * HID + lane];
    if (DO_ELU) v = v > 0.f ? v : expm1f(v);
    size_t oi = (size_t)n * (H * HID) + hh * HID + lane;
    if (SPLITOUT) {
      unsigned short hb = f2bf(v);
      outHi[oi] = hb;
      outLo[oi] = f2bf(v - bf2f(hb));
    } else {
      outF[oi] = v;
    }
  }
}

extern "C" void kernel_launch(void* const* d_in, const int* in_sizes, int n_in,
                              void* d_out, int out_size, void* d_ws, size_t ws_size,
                              hipStream_t stream) {
  const float* feat = (const float*)d_in[0];
  const int* src = (const int*)d_in[1];
  const int* dst = (const int*)d_in[2];
  const float* W1 = (const float*)d_in[3];
  const float* al1 = (const float*)d_in[4];
  const float* ar1 = (const float*)d_in[5];
  const float* b1 = (const float*)d_in[6];
  const float* W2 = (const float*)d_in[7];
  const float* al2 = (const float*)d_in[8];
  const float* ar2 = (const float*)d_in[9];
  const float* b2 = (const float*)d_in[10];
  const float* W3 = (const float*)d_in[11];
  const float* al3 = (const float*)d_in[12];
  const float* ar3 = (const float*)d_in[13];
  const float* b3 = (const float*)d_in[14];
  const int N = in_sizes[0] / 128;  // 50000
  const int E = in_sizes[1];        // 800000

  char* w = (char*)d_ws;
  auto alloc = [&](size_t bytes) {
    void* p = (void*)w;
    w += (bytes + 255) & ~(size_t)255;
    return p;
  };
  unsigned short* pHi = (unsigned short*)alloc((size_t)N * 256 * 2);  // GEMM A hi
  unsigned short* pLo = (unsigned short*)alloc((size_t)N * 256 * 2);  // GEMM A lo
  float* Cbuf = (float*)alloc((size_t)N * 256 * 4);                   // post-GEMM h (f32)
  unsigned short* Gp = (unsigned short*)alloc((size_t)N * 256 * 2);   // packed bf16 gather copy
  float* el = (float*)alloc((size_t)N * 4 * 4);
  float* er = (float*)alloc((size_t)N * 4 * 4);
  int* deg = (int*)alloc((size_t)N * 4);
  int* cursor = (int*)alloc((size_t)N * 4);
  int* offs = (int*)alloc((size_t)(N + 1) * 4);
  int nb = (N + SB - 1) / SB;
  int* bsums = (int*)alloc((size_t)nb * 4);
  int* carry = (int*)alloc((size_t)nb * 4);
  int* esrc = (int*)alloc((size_t)E * 4);
  unsigned short* W1h = (unsigned short*)alloc((size_t)256 * 128 * 2);
  unsigned short* W1l = (unsigned short*)alloc((size_t)256 * 128 * 2);
  unsigned short* W2h = (unsigned short*)alloc((size_t)256 * 256 * 2);
  unsigned short* W2l = (unsigned short*)alloc((size_t)256 * 256 * 2);
  unsigned short* W3h = (unsigned short*)alloc((size_t)64 * 256 * 2);
  unsigned short* W3l = (unsigned short*)alloc((size_t)64 * 256 * 2);

  // ---- CSR by dst ----
  hipMemsetAsync(deg, 0, (size_t)N * 4, stream);
  hipMemsetAsync(cursor, 0, (size_t)N * 4, stream);
  int eb = (E + 255) / 256;
  k_count<<<eb, 256, 0, stream>>>(dst, deg, E);
  k_blocksums<<<nb, SB, 0, stream>>>(deg, bsums, N);
  k_scancarry<<<1, SB, 0, stream>>>(bsums, carry, nb);
  k_offsets<<<nb, SB, 0, stream>>>(deg, carry, offs, N, E);
  k_fill<<<eb, 256, 0, stream>>>(src, dst, offs, cursor, esrc, E);

  // ---- weight transpose+split ----
  k_wsplit<<<(256 * 128 + 255) / 256, 256, 0, stream>>>(W1, W1h, W1l, 128, 256);
  k_wsplit<<<(256 * 256 + 255) / 256, 256, 0, stream>>>(W2, W2h, W2l, 256, 256);
  k_wsplit<<<(64 * 256 + 255) / 256, 256, 0, stream>>>(W3, W3h, W3l, 256, 64);

  // ---- feat split ----
  k_split<<<((N * 128) + 255) / 256, 256, 0, stream>>>(feat, pHi, pLo, N * 128);

  int rg = (N + 127) / 128;  // 391
  // ---- layer 1: [N,128] @ W1 -> [N,256] ----
  gemm_split<<<dim3(2, rg), 256, 0, stream>>>(pHi, pLo, W1h, W1l, Cbuf, Gp, N, 256, 128, 4);
  elr_kernel<<<N, 64, 0, stream>>>(Cbuf, al1, ar1, el, er, 4);
  agg_kernel<4, true, true><<<N, 64, 0, stream>>>(Gp, el, er, offs, esrc, b1, pHi, pLo, nullptr);
  // ---- layer 2: [N,256] @ W2 -> [N,256] ----
  gemm_split<<<dim3(2, rg), 256, 0, stream>>>(pHi, pLo, W2h, W2l, Cbuf, Gp, N, 256, 256, 4);
  elr_kernel<<<N, 64, 0, stream>>>(Cbuf, al2, ar2, el, er, 4);
  agg_kernel<4, true, true><<<N, 64, 0, stream>>>(Gp, el, er, offs, esrc, b2, pHi, pLo, nullptr);
  // ---- layer 3: [N,256] @ W3 -> [N,64], single head, mean == identity ----
  gemm_split<<<dim3(1, rg), 256, 0, stream>>>(pHi, pLo, W3h, W3l, Cbuf, Gp, N, 64, 256, 1);
  elr_kernel<<<N, 64, 0, stream>>>(Cbuf, al3, ar3, el, er, 1);
  agg_kernel<1, false, false><<<N, 64, 0, stream>>>(Gp, el, er, offs, esrc, b3, nullptr, nullptr, (float*)d_out);
}